// Round 7
// baseline (142.042 us; speedup 1.0000x reference)
//
#include <hip/hip_runtime.h>

#define J_NUM 24
#define BLOCK 64        // one wave per block; barriers degenerate to s_waitcnt
#define PSTRIDE 73      // pose element stride in LDS (odd -> scalar reads conflict-free)
#define OSTRIDE 76      // output element stride (16B aligned -> b128, bank stride 19 -> free)
#define LDS_FLOATS (BLOCK * OSTRIDE)   // 19456 B -> 8 blocks/CU in 160 KiB

__global__ __launch_bounds__(BLOCK, 2)
void fk_kernel(const float* __restrict__ pose, const float* __restrict__ trans,
               const float* __restrict__ Jm, float* __restrict__ out)
{
    __shared__ __align__(16) float s[LDS_FLOATS];  // pose (stride 73), then outputs (stride 76)

    const int t = threadIdx.x;
    const size_t blockBase = (size_t)blockIdx.x * BLOCK;
    const size_t b = blockBase + t;

    // ---- phase 1: dense coalesced float4 global loads -> LDS at stride 73 ----
    {
        const float4* src = reinterpret_cast<const float4*>(pose + blockBase * 72);
#pragma unroll
        for (int i = 0; i < 18; ++i) {
            int m = i * BLOCK + t;          // float4 index 0..1151
            float4 v = src[m];
            int e = m / 18;
            int f = (m - e * 18) * 4;
            float* d = s + e * PSTRIDE + f;
            d[0] = v.x; d[1] = v.y; d[2] = v.z; d[3] = v.w;
        }
    }

    const float t0 = trans[b*3 + 0];
    const float t1 = trans[b*3 + 1];
    const float t2 = trans[b*3 + 2];

    __syncthreads();

    // this thread's pose: s[t*73 + 0..71]; scalar reads bank=(9t+c)%32 -> 2-way, free
    const float* p = s + t * PSTRIDE;

    const int par[J_NUM] = {-1,0,0,0,1,2,3,4,5,6,7,8,9,9,9,12,13,14,16,17,18,19,20,21};

    float Rc[J_NUM][9];   // SROA'd; live set ~5 matrices at peak
    float Pc[J_NUM][3];
    float o[72];          // outputs; peak pressure hits only at loop end when Rc is dead

#pragma unroll
    for (int j = 0; j < J_NUM; ++j) {
        float ax = p[j*3+0], ay = p[j*3+1], az = p[j*3+2];
        float tt = fmaf(ax, ax, fmaf(ay, ay, fmaf(az, az, 1e-16f)));
        float inv = rsqrtf(tt);
        float th  = tt * inv;               // sqrt(tt)
        float x = ax*inv, y = ay*inv, z = az*inv;
        float c = __cosf(th), sn = __sinf(th);
        float C = 1.0f - c;
        float cx = C*x, cy = C*y, cz = C*z;
        float sx = sn*x, sy = sn*y, sz = sn*z;
        float R0 = fmaf(cx, x, c);
        float R1 = fmaf(cx, y, -sz);
        float R2 = fmaf(cx, z,  sy);
        float R3 = fmaf(cy, x,  sz);
        float R4 = fmaf(cy, y, c);
        float R5 = fmaf(cy, z, -sx);
        float R6 = fmaf(cz, x, -sy);
        float R7 = fmaf(cz, y,  sx);
        float R8 = fmaf(cz, z, c);

        // rest-pose local offset (wave-uniform -> scalar loads)
        float ox = Jm[j*16 + 3];
        float oy = Jm[j*16 + 7];
        float oz = Jm[j*16 + 11];

        if (j == 0) {
            Rc[0][0]=R0; Rc[0][1]=R1; Rc[0][2]=R2;
            Rc[0][3]=R3; Rc[0][4]=R4; Rc[0][5]=R5;
            Rc[0][6]=R6; Rc[0][7]=R7; Rc[0][8]=R8;
            Pc[0][0]=ox; Pc[0][1]=oy; Pc[0][2]=oz;
        } else {
            const int q = par[j];
            Pc[j][0] = fmaf(Rc[q][0], ox, fmaf(Rc[q][1], oy, fmaf(Rc[q][2], oz, Pc[q][0])));
            Pc[j][1] = fmaf(Rc[q][3], ox, fmaf(Rc[q][4], oy, fmaf(Rc[q][5], oz, Pc[q][1])));
            Pc[j][2] = fmaf(Rc[q][6], ox, fmaf(Rc[q][7], oy, fmaf(Rc[q][8], oz, Pc[q][2])));
            Rc[j][0] = fmaf(Rc[q][0], R0, fmaf(Rc[q][1], R3, Rc[q][2]*R6));
            Rc[j][1] = fmaf(Rc[q][0], R1, fmaf(Rc[q][1], R4, Rc[q][2]*R7));
            Rc[j][2] = fmaf(Rc[q][0], R2, fmaf(Rc[q][1], R5, Rc[q][2]*R8));
            Rc[j][3] = fmaf(Rc[q][3], R0, fmaf(Rc[q][4], R3, Rc[q][5]*R6));
            Rc[j][4] = fmaf(Rc[q][3], R1, fmaf(Rc[q][4], R4, Rc[q][5]*R7));
            Rc[j][5] = fmaf(Rc[q][3], R2, fmaf(Rc[q][4], R5, Rc[q][5]*R8));
            Rc[j][6] = fmaf(Rc[q][6], R0, fmaf(Rc[q][7], R3, Rc[q][8]*R6));
            Rc[j][7] = fmaf(Rc[q][6], R1, fmaf(Rc[q][7], R4, Rc[q][8]*R7));
            Rc[j][8] = fmaf(Rc[q][6], R2, fmaf(Rc[q][7], R5, Rc[q][8]*R8));
        }

        o[j*3+0] = Pc[j][0] + t0;
        o[j*3+1] = Pc[j][1] + t1;
        o[j*3+2] = Pc[j][2] + t2;
    }

    // all pose reads done before the output region (different stride) overwrites them
    __syncthreads();

    // ---- phase 2: regs -> LDS, 18 x ds_write_b128 at stride 76 (bank stride 19: free) ----
    {
        float* mine = s + t * OSTRIDE;
#pragma unroll
        for (int k = 0; k < 18; ++k) {
            float4 v;
            v.x = o[4*k+0]; v.y = o[4*k+1]; v.z = o[4*k+2]; v.w = o[4*k+3];
            *reinterpret_cast<float4*>(mine + 4*k) = v;
        }
    }

    __syncthreads();

    // ---- phase 3: b128 LDS reads -> dense coalesced global float4 stores ----
    {
        float4* dst = reinterpret_cast<float4*>(out + blockBase * 72);
#pragma unroll
        for (int i = 0; i < 18; ++i) {
            int m = i * BLOCK + t;
            int e = m / 18;
            int f = (m - e * 18) * 4;
            float4 v = *reinterpret_cast<const float4*>(s + e * OSTRIDE + f);
            dst[m] = v;
        }
    }
}

extern "C" void kernel_launch(void* const* d_in, const int* in_sizes, int n_in,
                              void* d_out, int out_size, void* d_ws, size_t ws_size,
                              hipStream_t stream) {
    const float* pose  = (const float*)d_in[0];
    const float* trans = (const float*)d_in[1];
    const float* Jm    = (const float*)d_in[2];
    float* out = (float*)d_out;

    int B = in_sizes[0] / (J_NUM * 3);   // 131072
    int blocks = B / BLOCK;              // 2048

    // MEASUREMENT ROUND: fk is idempotent; 4 identical launches make
    // fk_warm = (total - 93.13us) / 3 directly readable from the bench total.
    // (Same work every call -> graph-capture safe.)
    for (int rep = 0; rep < 4; ++rep)
        fk_kernel<<<blocks, BLOCK, 0, stream>>>(pose, trans, Jm, out);
}

// Round 8
// 95.634 us; speedup vs baseline: 1.4853x; 1.4853x over previous
//
#include <hip/hip_runtime.h>

#define J_NUM 24
#define BLOCK 64          // one wave per block: "barriers" are wave-local, no vmcnt drain
#define PSTRIDE 73        // pose LDS stride (odd -> scalar compute reads 2-way, free)
#define OSTRIDE 76        // out LDS stride (304 B: 16B-aligned b128, bank stride 19, free)
#define EPB 128           // elements per block: two pipelined halves of 64

// Wave-local sync: waits LDS ops only; global loads/stores stay in flight
// (unlike __syncthreads(), which drains vmcnt(0) before s_barrier).
#define WAVE_SYNC() do { asm volatile("s_waitcnt lgkmcnt(0)" ::: "memory"); \
                         __builtin_amdgcn_wave_barrier(); } while (0)

__device__ __forceinline__ void compute_elem(const float* __restrict__ p,
                                             const float* __restrict__ Jm,
                                             float t0, float t1, float t2,
                                             float* __restrict__ o)
{
    const int par[J_NUM] = {-1,0,0,0,1,2,3,4,5,6,7,8,9,9,9,12,13,14,16,17,18,19,20,21};
    float Rc[J_NUM][9];
    float Pc[J_NUM][3];
#pragma unroll
    for (int j = 0; j < J_NUM; ++j) {
        float ax = p[j*3+0], ay = p[j*3+1], az = p[j*3+2];
        float tt = fmaf(ax, ax, fmaf(ay, ay, fmaf(az, az, 1e-16f)));
        float inv = rsqrtf(tt);
        float th  = tt * inv;
        float x = ax*inv, y = ay*inv, z = az*inv;
        float c = __cosf(th), sn = __sinf(th);
        float C = 1.0f - c;
        float cx = C*x, cy = C*y, cz = C*z;
        float sx = sn*x, sy = sn*y, sz = sn*z;
        float R0 = fmaf(cx, x, c);
        float R1 = fmaf(cx, y, -sz);
        float R2 = fmaf(cx, z,  sy);
        float R3 = fmaf(cy, x,  sz);
        float R4 = fmaf(cy, y, c);
        float R5 = fmaf(cy, z, -sx);
        float R6 = fmaf(cz, x, -sy);
        float R7 = fmaf(cz, y,  sx);
        float R8 = fmaf(cz, z, c);

        float ox = Jm[j*16 + 3];
        float oy = Jm[j*16 + 7];
        float oz = Jm[j*16 + 11];

        if (j == 0) {
            Rc[0][0]=R0; Rc[0][1]=R1; Rc[0][2]=R2;
            Rc[0][3]=R3; Rc[0][4]=R4; Rc[0][5]=R5;
            Rc[0][6]=R6; Rc[0][7]=R7; Rc[0][8]=R8;
            Pc[0][0]=ox; Pc[0][1]=oy; Pc[0][2]=oz;
        } else {
            const int q = par[j];
            Pc[j][0] = fmaf(Rc[q][0], ox, fmaf(Rc[q][1], oy, fmaf(Rc[q][2], oz, Pc[q][0])));
            Pc[j][1] = fmaf(Rc[q][3], ox, fmaf(Rc[q][4], oy, fmaf(Rc[q][5], oz, Pc[q][1])));
            Pc[j][2] = fmaf(Rc[q][6], ox, fmaf(Rc[q][7], oy, fmaf(Rc[q][8], oz, Pc[q][2])));
            Rc[j][0] = fmaf(Rc[q][0], R0, fmaf(Rc[q][1], R3, Rc[q][2]*R6));
            Rc[j][1] = fmaf(Rc[q][0], R1, fmaf(Rc[q][1], R4, Rc[q][2]*R7));
            Rc[j][2] = fmaf(Rc[q][0], R2, fmaf(Rc[q][1], R5, Rc[q][2]*R8));
            Rc[j][3] = fmaf(Rc[q][3], R0, fmaf(Rc[q][4], R3, Rc[q][5]*R6));
            Rc[j][4] = fmaf(Rc[q][3], R1, fmaf(Rc[q][4], R4, Rc[q][5]*R7));
            Rc[j][5] = fmaf(Rc[q][3], R2, fmaf(Rc[q][4], R5, Rc[q][5]*R8));
            Rc[j][6] = fmaf(Rc[q][6], R0, fmaf(Rc[q][7], R3, Rc[q][8]*R6));
            Rc[j][7] = fmaf(Rc[q][6], R1, fmaf(Rc[q][7], R4, Rc[q][8]*R7));
            Rc[j][8] = fmaf(Rc[q][6], R2, fmaf(Rc[q][7], R5, Rc[q][8]*R8));
        }

        o[j*3+0] = Pc[j][0] + t0;
        o[j*3+1] = Pc[j][1] + t1;
        o[j*3+2] = Pc[j][2] + t2;
    }
}

__global__ __launch_bounds__(BLOCK)
void fk_kernel(const float* __restrict__ pose, const float* __restrict__ trans,
               const float* __restrict__ Jm, float* __restrict__ out)
{
    __shared__ __align__(16) float sp[BLOCK * PSTRIDE];  // 18688 B, pose staging
    __shared__ __align__(16) float so[BLOCK * OSTRIDE];  // 19456 B, output staging
    // 38144 B total -> 4 blocks/CU; 1024 blocks = 4/CU: whole grid resident

    const int t = threadIdx.x;
    const size_t base = (size_t)blockIdx.x * EPB;      // first element of half 0
    const size_t b0 = base + t;
    const size_t b1 = base + 64 + t;

    // ---- issue half-0 loads ----
    float4 L0[18];
    {
        const float4* src = reinterpret_cast<const float4*>(pose + base * 72);
#pragma unroll
        for (int i = 0; i < 18; ++i) L0[i] = src[i * BLOCK + t];
    }
    const float a0 = trans[b0*3+0], a1 = trans[b0*3+1], a2 = trans[b0*3+2];

    // ---- ds_write pose0 (waits vmcnt on L0 only) ----
#pragma unroll
    for (int i = 0; i < 18; ++i) {
        int m = i * BLOCK + t;
        int e = m / 18;
        int f = (m - e * 18) * 4;
        float* d = sp + e * PSTRIDE + f;
        d[0] = L0[i].x; d[1] = L0[i].y; d[2] = L0[i].z; d[3] = L0[i].w;
    }

    // ---- issue half-1 loads NOW: in flight across half-0 compute + stores ----
    float4 L1[18];
    {
        const float4* src = reinterpret_cast<const float4*>(pose + (base + 64) * 72);
#pragma unroll
        for (int i = 0; i < 18; ++i) L1[i] = src[i * BLOCK + t];
    }
    const float c0 = trans[b1*3+0], c1 = trans[b1*3+1], c2 = trans[b1*3+2];

    WAVE_SYNC();   // pose0 visible; L1 loads remain outstanding

    float o0[72];
    compute_elem(sp + t * PSTRIDE, Jm, a0, a1, a2, o0);

    // ---- stage o0 -> so (b128, stride 76) ----
    {
        float* mine = so + t * OSTRIDE;
#pragma unroll
        for (int k = 0; k < 18; ++k) {
            float4 v; v.x=o0[4*k+0]; v.y=o0[4*k+1]; v.z=o0[4*k+2]; v.w=o0[4*k+3];
            *reinterpret_cast<float4*>(mine + 4*k) = v;
        }
    }
    WAVE_SYNC();

    // ---- dense stores half 0 (drain overlaps half-1 ds_write/compute) ----
    {
        float4* dst = reinterpret_cast<float4*>(out + base * 72);
#pragma unroll
        for (int i = 0; i < 18; ++i) {
            int m = i * BLOCK + t;
            int e = m / 18;
            int f = (m - e * 18) * 4;
            dst[m] = *reinterpret_cast<const float4*>(so + e * OSTRIDE + f);
        }
    }

    // ---- ds_write pose1 (waits vmcnt(L1) which is vmcnt(18): stores keep draining) ----
#pragma unroll
    for (int i = 0; i < 18; ++i) {
        int m = i * BLOCK + t;
        int e = m / 18;
        int f = (m - e * 18) * 4;
        float* d = sp + e * PSTRIDE + f;
        d[0] = L1[i].x; d[1] = L1[i].y; d[2] = L1[i].z; d[3] = L1[i].w;
    }
    WAVE_SYNC();

    float o1[72];
    compute_elem(sp + t * PSTRIDE, Jm, c0, c1, c2, o1);

    {
        float* mine = so + t * OSTRIDE;
#pragma unroll
        for (int k = 0; k < 18; ++k) {
            float4 v; v.x=o1[4*k+0]; v.y=o1[4*k+1]; v.z=o1[4*k+2]; v.w=o1[4*k+3];
            *reinterpret_cast<float4*>(mine + 4*k) = v;
        }
    }
    WAVE_SYNC();

    {
        float4* dst = reinterpret_cast<float4*>(out + (base + 64) * 72);
#pragma unroll
        for (int i = 0; i < 18; ++i) {
            int m = i * BLOCK + t;
            int e = m / 18;
            int f = (m - e * 18) * 4;
            dst[m] = *reinterpret_cast<const float4*>(so + e * OSTRIDE + f);
        }
    }
}

extern "C" void kernel_launch(void* const* d_in, const int* in_sizes, int n_in,
                              void* d_out, int out_size, void* d_ws, size_t ws_size,
                              hipStream_t stream) {
    const float* pose  = (const float*)d_in[0];
    const float* trans = (const float*)d_in[1];
    const float* Jm    = (const float*)d_in[2];
    float* out = (float*)d_out;

    int B = in_sizes[0] / (J_NUM * 3);   // 131072
    int blocks = B / EPB;                // 1024
    fk_kernel<<<blocks, BLOCK, 0, stream>>>(pose, trans, Jm, out);
}